// Round 1
// baseline (282.039 us; speedup 1.0000x reference)
//
#include <hip/hip_runtime.h>
#include <hip/hip_bf16.h>

#define N_ATOMS 131072
#define DQ 256
#define H1 512
#define NTYPES 4
#define TILE_M 64
#define NPAD (N_ATOMS + NTYPES * TILE_M)       // 131328
#define MTILES ((N_ATOMS / TILE_M) + NTYPES)   // 2052

typedef __bf16 bf16x8 __attribute__((ext_vector_type(8)));
typedef float f32x16 __attribute__((ext_vector_type(16)));

__device__ __forceinline__ unsigned short f2bf(float f) {
  unsigned int u = __builtin_bit_cast(unsigned int, f);
  u += 0x7fffu + ((u >> 16) & 1u);   // round-to-nearest-even (inputs finite)
  return (unsigned short)(u >> 16);
}

__device__ __forceinline__ float fast_tanh(float x) {
  // tanh(x) = 1 - 2/(exp(2x)+1); exp overflow -> +1, underflow -> -1. NaN-free.
  float e = __expf(2.0f * x);
  return 1.0f - 2.0f * __builtin_amdgcn_rcpf(e + 1.0f);
}

// ---------------------------------------------------------------------------
// prep: (a) perm[] = -1, (b) W0 fp32 -> bf16 pre-swizzled [t][k/8][n][8k],
//       (c) per-block histogram of Z (no global atomics, no pre-zeroed mem)
// ---------------------------------------------------------------------------
__global__ __launch_bounds__(256) void prep_kernel(
    const float* __restrict__ W0, const int* __restrict__ Z,
    unsigned short* __restrict__ W0s, int* __restrict__ perm,
    int* __restrict__ blockcounts)
{
  const int b = blockIdx.x, tid = threadIdx.x;
  const int gid = b * 256 + tid;

  for (int i = gid; i < NPAD; i += 512 * 256) perm[i] = -1;

  if (gid < NTYPES * (DQ / 8) * H1) {   // 65536 16-byte chunks
    const int n  = gid & (H1 - 1);
    const int kg = (gid >> 9) & 31;
    const int t  = gid >> 14;
    const float* src = W0 + ((size_t)(t * DQ + kg * 8) * H1 + n);
    unsigned short o[8];
#pragma unroll
    for (int j = 0; j < 8; ++j) o[j] = f2bf(src[(size_t)j * H1]);
    uint4 v;
    v.x = (unsigned)o[0] | ((unsigned)o[1] << 16);
    v.y = (unsigned)o[2] | ((unsigned)o[3] << 16);
    v.z = (unsigned)o[4] | ((unsigned)o[5] << 16);
    v.w = (unsigned)o[6] | ((unsigned)o[7] << 16);
    ((uint4*)W0s)[gid] = v;
  }

  __shared__ int lc[NTYPES];
  if (tid < NTYPES) lc[tid] = 0;
  __syncthreads();
  atomicAdd(&lc[Z[gid]], 1);            // grid 512*256 == N exactly
  __syncthreads();
  if (tid < NTYPES) blockcounts[b * NTYPES + tid] = lc[tid];
}

// ---------------------------------------------------------------------------
// scan: reduce per-block histograms -> padded (x64) segment offsets + cursors
// ---------------------------------------------------------------------------
__global__ __launch_bounds__(256) void scan_kernel(
    const int* __restrict__ blockcounts, int* __restrict__ padded_off,
    int* __restrict__ cursors)
{
  __shared__ int sums[NTYPES];
  const int tid = threadIdx.x;
  if (tid < NTYPES) sums[tid] = 0;
  __syncthreads();
  const int t = tid & 3;
  int acc = 0;
  for (int b = tid >> 2; b < 512; b += 64) acc += blockcounts[b * 4 + t];
  atomicAdd(&sums[t], acc);
  __syncthreads();
  if (tid == 0) {
    int off = 0;
#pragma unroll
    for (int i = 0; i < NTYPES; ++i) {
      padded_off[i] = off;
      cursors[i] = off;
      off += (sums[i] + TILE_M - 1) & ~(TILE_M - 1);
    }
    padded_off[NTYPES] = off;
  }
}

// ---------------------------------------------------------------------------
// scatter: block-aggregated (4 global atomics per block) type binning
// ---------------------------------------------------------------------------
__global__ __launch_bounds__(256) void scatter_kernel(
    const int* __restrict__ Z, int* __restrict__ cursors, int* __restrict__ perm)
{
  __shared__ int lc[NTYPES], lbase[NTYPES];
  const int tid = threadIdx.x;
  const int gid = blockIdx.x * 256 + tid;
  if (tid < NTYPES) lc[tid] = 0;
  __syncthreads();
  const int t  = Z[gid];
  const int my = atomicAdd(&lc[t], 1);
  __syncthreads();
  if (tid < NTYPES) lbase[tid] = lc[tid] ? atomicAdd(&cursors[tid], lc[tid]) : 0;
  __syncthreads();
  perm[lbase[t] + my] = gid;
}

// ---------------------------------------------------------------------------
// gemm: per block, 64 gathered q rows x all 512 cols of W0[t], fused
// tanh + W1-dot epilogue. A in LDS (bf16, fragment layout), B straight
// from L2 (pre-swizzled W0s) -> zero barriers inside the K-loop.
// ---------------------------------------------------------------------------
__global__ __launch_bounds__(256, 2) void gemm_kernel(
    const float* __restrict__ q, const int* __restrict__ perm,
    const int* __restrict__ padded_off, const unsigned short* __restrict__ W0s,
    const float* __restrict__ b0, const float* __restrict__ W1,
    const float* __restrict__ b1p, float* __restrict__ out)
{
  __shared__ unsigned short Alds[(DQ / 8) * TILE_M * 8];  // 32 KB, [k/8][m][8]
  __shared__ float Fws[4][TILE_M];

  const int gr0 = blockIdx.x * TILE_M;
  if (gr0 >= padded_off[NTYPES]) return;      // uniform early-exit
  int t = 0;
#pragma unroll
  for (int i = 1; i < NTYPES; ++i) t += (gr0 >= padded_off[i]) ? 1 : 0;

  const int tid = threadIdx.x;

  // ---- stage A: 64 rows x 256 k, fp32 -> bf16, gathered via perm ----
  {
    const int row = tid >> 2, c4 = tid & 3;
    const int atom = perm[gr0 + row];
    const float* qrow = q + (size_t)(atom < 0 ? 0 : atom) * DQ;
#pragma unroll
    for (int i = 0; i < 16; ++i) {
      const int k = c4 * 64 + i * 4;
      float4 v = make_float4(0.f, 0.f, 0.f, 0.f);
      if (atom >= 0) v = *(const float4*)(qrow + k);
      ushort4 o;
      o.x = f2bf(v.x); o.y = f2bf(v.y); o.z = f2bf(v.z); o.w = f2bf(v.w);
      *(ushort4*)&Alds[((k >> 3) * TILE_M + row) * 8 + (k & 7)] = o;
    }
  }
  __syncthreads();

  const int l = tid & 63, w = tid >> 6;
  const int half = l >> 5, ln = l & 31;

  f32x16 acc[2][4];
#pragma unroll
  for (int mt = 0; mt < 2; ++mt)
#pragma unroll
    for (int nt = 0; nt < 4; ++nt) acc[mt][nt] = (f32x16)0.0f;

  const unsigned short* Bt = W0s + (size_t)t * (DQ * H1);
  const unsigned short* Bbase = Bt + (size_t)(w * 128 + ln) * 8;

#pragma unroll 4
  for (int step = 0; step < 16; ++step) {
    const int kg = 2 * step + half;
    const bf16x8 a0 = *(const bf16x8*)&Alds[(kg * TILE_M + ln) * 8];
    const bf16x8 a1 = *(const bf16x8*)&Alds[(kg * TILE_M + 32 + ln) * 8];
    const unsigned short* bp = Bbase + (size_t)kg * (H1 * 8);
    const bf16x8 b0f = *(const bf16x8*)(bp);
    const bf16x8 b1f = *(const bf16x8*)(bp + 32 * 8);
    const bf16x8 b2f = *(const bf16x8*)(bp + 64 * 8);
    const bf16x8 b3f = *(const bf16x8*)(bp + 96 * 8);
    acc[0][0] = __builtin_amdgcn_mfma_f32_32x32x16_bf16(a0, b0f, acc[0][0], 0, 0, 0);
    acc[1][0] = __builtin_amdgcn_mfma_f32_32x32x16_bf16(a1, b0f, acc[1][0], 0, 0, 0);
    acc[0][1] = __builtin_amdgcn_mfma_f32_32x32x16_bf16(a0, b1f, acc[0][1], 0, 0, 0);
    acc[1][1] = __builtin_amdgcn_mfma_f32_32x32x16_bf16(a1, b1f, acc[1][1], 0, 0, 0);
    acc[0][2] = __builtin_amdgcn_mfma_f32_32x32x16_bf16(a0, b2f, acc[0][2], 0, 0, 0);
    acc[1][2] = __builtin_amdgcn_mfma_f32_32x32x16_bf16(a1, b2f, acc[1][2], 0, 0, 0);
    acc[0][3] = __builtin_amdgcn_mfma_f32_32x32x16_bf16(a0, b3f, acc[0][3], 0, 0, 0);
    acc[1][3] = __builtin_amdgcn_mfma_f32_32x32x16_bf16(a1, b3f, acc[1][3], 0, 0, 0);
  }

  // ---- epilogue: h = tanh(acc + b0), partial F = h . W1 ----
  float b0v[4], w1v[4];
#pragma unroll
  for (int nt = 0; nt < 4; ++nt) {
    const int c = w * 128 + nt * 32 + ln;
    b0v[nt] = b0[t * H1 + c];
    w1v[nt] = W1[t * H1 + c];
  }
#pragma unroll
  for (int mt = 0; mt < 2; ++mt) {
#pragma unroll
    for (int r = 0; r < 16; ++r) {
      float s = 0.f;
#pragma unroll
      for (int nt = 0; nt < 4; ++nt)
        s += w1v[nt] * fast_tanh(acc[mt][nt][r] + b0v[nt]);
      // reduce over the 32 cols held across lanes (masks stay within 32-half)
      s += __shfl_xor(s, 1);
      s += __shfl_xor(s, 2);
      s += __shfl_xor(s, 4);
      s += __shfl_xor(s, 8);
      s += __shfl_xor(s, 16);
      if (ln == 0)
        Fws[w][mt * 32 + (r & 3) + 8 * (r >> 2) + 4 * half] = s;
    }
  }
  __syncthreads();

  if (tid < TILE_M) {
    const int atom = perm[gr0 + tid];
    if (atom >= 0)
      out[atom] = Fws[0][tid] + Fws[1][tid] + Fws[2][tid] + Fws[3][tid] + b1p[0];
  }
}

extern "C" void kernel_launch(void* const* d_in, const int* in_sizes, int n_in,
                              void* d_out, int out_size, void* d_ws, size_t ws_size,
                              hipStream_t stream) {
  const float* q  = (const float*)d_in[0];
  const int*   Z  = (const int*)d_in[1];
  const float* W0 = (const float*)d_in[2];
  const float* b0 = (const float*)d_in[3];
  const float* W1 = (const float*)d_in[4];
  const float* b1 = (const float*)d_in[5];
  float* out = (float*)d_out;

  char* ws = (char*)d_ws;
  int* blockcounts = (int*)(ws);                          // 512*4 ints = 8 KB
  int* padded_off  = (int*)(ws + 8192);                   // 5 ints
  int* cursors     = (int*)(ws + 8192 + 32);              // 4 ints
  int* perm        = (int*)(ws + 8192 + 64);              // NPAD ints = 513 KB
  unsigned short* W0s = (unsigned short*)(ws + 8192 + 64 + (size_t)NPAD * 4); // 1 MB

  hipLaunchKernelGGL(prep_kernel,    dim3(512),    dim3(256), 0, stream, W0, Z, W0s, perm, blockcounts);
  hipLaunchKernelGGL(scan_kernel,    dim3(1),      dim3(256), 0, stream, blockcounts, padded_off, cursors);
  hipLaunchKernelGGL(scatter_kernel, dim3(512),    dim3(256), 0, stream, Z, cursors, perm);
  hipLaunchKernelGGL(gemm_kernel,    dim3(MTILES), dim3(256), 0, stream, q, perm, padded_off, W0s, b0, W1, b1, out);
}